// Round 2
// baseline (432.221 us; speedup 1.0000x reference)
//
#include <hip/hip_runtime.h>
#include <hip/hip_bf16.h>
#include <stdint.h>
#include <stddef.h>

using bf16 = __hip_bfloat16;
typedef short short8 __attribute__((ext_vector_type(8)));
typedef float f32x4 __attribute__((ext_vector_type(4)));

#define MFMA16(A, B, C) __builtin_amdgcn_mfma_f32_16x16x32_bf16(A, B, C, 0, 0, 0)

// Problem constants
constexpr int AN  = 4096;   // sequence length N
constexpr int NH  = 16;     // heads
constexpr int HD  = 64;     // head dim
constexpr int CC  = 1024;   // channels = NH*HD
constexpr int C3  = 3072;   // 3*CC
constexpr float SCALE = 0.125f;  // D^-0.5

__device__ inline short bf16s(float f) {
    bf16 h = __float2bfloat16(f);
    return *reinterpret_cast<short*>(&h);
}

// ---------------------------------------------------------------------------
// Dtype auto-detect: mode=1 -> inputs are fp32 (expected), mode=0 -> bf16.
// fp32 data read as bf16 has ~45% wild exponents (low mantissa halves);
// true bf16 N(0,1) has essentially none.
// ---------------------------------------------------------------------------
__global__ void detect_mode(const unsigned short* __restrict__ xraw,
                            int* __restrict__ mode) {
    const int lane = threadIdx.x;   // 64 threads
    int crazy = 0;
    #pragma unroll
    for (int i = 0; i < 4; ++i) {
        const unsigned short u = xraw[lane * 4 + i];
        const int e = (u >> 7) & 0xFF;              // bf16 exponent field
        if (e >= 134 || (e != 0 && e <= 110)) ++crazy;  // |v|>=128 or <=7.6e-6
    }
    #pragma unroll
    for (int off = 32; off > 0; off >>= 1)
        crazy += __shfl_down(crazy, off, 64);
    if (lane == 0) *mode = (crazy >= 8) ? 1 : 0;
}

// Cast n elements (n % 8 == 0) to bf16; pass-through copy if already bf16.
__global__ void cast_in(const void* __restrict__ src, bf16* __restrict__ dst,
                        int n, const int* __restrict__ mode) {
    const int i = (blockIdx.x * blockDim.x + threadIdx.x) * 8;
    if (i >= n) return;
    if (*mode) {
        const float* s = (const float*)src;
        float4 a = *(const float4*)(s + i);
        float4 b = *(const float4*)(s + i + 4);
        short8 o;
        o[0] = bf16s(a.x); o[1] = bf16s(a.y); o[2] = bf16s(a.z); o[3] = bf16s(a.w);
        o[4] = bf16s(b.x); o[5] = bf16s(b.y); o[6] = bf16s(b.z); o[7] = bf16s(b.w);
        *(short8*)(dst + i) = o;
    } else {
        *(short8*)(dst + i) = *(const short8*)((const short*)src + i);
    }
}

__global__ void cast_bias(const void* __restrict__ src, float* __restrict__ dst,
                          int n, const int* __restrict__ mode) {
    const int i = blockIdx.x * blockDim.x + threadIdx.x;
    if (i >= n) return;
    dst[i] = (*mode) ? ((const float*)src)[i]
                     : __bfloat162float(((const bf16*)src)[i]);
}

// ---------------------------------------------------------------------------
// GEMM (B-transposed weights): C[m][o] = sum_k A[m][k] * Bw[o][k] (+ bias[o])
// m97 structure: 128x128 tile, BK=32, global_load_lds width=16, 4 waves.
// OUT_BY_MODE: store fp32 when *mode==1, else bf16 (final proj writes d_out).
// ---------------------------------------------------------------------------
constexpr int BM = 128, BN = 128, BK = 32;

template<bool OUT_BY_MODE>
__global__ __launch_bounds__(256, 2) void gemm_bt(
    const bf16* __restrict__ A, const bf16* __restrict__ Bw,
    const float* __restrict__ bias, void* __restrict__ Cout,
    const int* __restrict__ mode, int M, int K, int O)
{
    __shared__ bf16 As[BM * BK];   // [row][k] row-major, no pad (global_load_lds)
    __shared__ bf16 Bs[BN * BK];

    const int tid  = threadIdx.x;
    const int wave = tid >> 6;
    const int lane = tid & 63;
    const int quad = lane >> 4;
    const int l16  = lane & 15;
    const int wr   = wave >> 1;
    const int wc   = wave & 1;
    const int m0   = blockIdx.y * BM;
    const int o0   = blockIdx.x * BN;
    const bool f32out = OUT_BY_MODE && (*mode != 0);

    const int srow = lane >> 2;        // 0..15 row within 16-row staging call
    const int scol = (lane & 3) * 8;   // k-element offset (16B chunk)

    f32x4 acc[4][4] = {};

    for (int k0 = 0; k0 < K; k0 += BK) {
        __syncthreads();
        #pragma unroll
        for (int c = 0; c < 2; ++c) {
            const int rbase = wave * 32 + c * 16;  // wave-uniform
            const bf16* gA = A + (size_t)(m0 + rbase + srow) * K + k0 + scol;
            __builtin_amdgcn_global_load_lds(
                (const __attribute__((address_space(1))) void*)gA,
                (__attribute__((address_space(3))) void*)&As[rbase * BK], 16, 0, 0);
            const bf16* gB = Bw + (size_t)(o0 + rbase + srow) * K + k0 + scol;
            __builtin_amdgcn_global_load_lds(
                (const __attribute__((address_space(1))) void*)gB,
                (__attribute__((address_space(3))) void*)&Bs[rbase * BK], 16, 0, 0);
        }
        __syncthreads();   // drains vmcnt before LDS use

        short8 af[4], bfr[4];
        #pragma unroll
        for (int i = 0; i < 4; ++i)   // A frag: A[m=l16][k=quad*8+j]
            af[i] = *(const short8*)&As[(wr * 64 + i * 16 + l16) * BK + quad * 8];
        #pragma unroll
        for (int j = 0; j < 4; ++j)   // B frag: B[k=quad*8+j][n=l16] = Bw[n][k]
            bfr[j] = *(const short8*)&Bs[(wc * 64 + j * 16 + l16) * BK + quad * 8];
        #pragma unroll
        for (int i = 0; i < 4; ++i)
            #pragma unroll
            for (int j = 0; j < 4; ++j)
                acc[i][j] = MFMA16(af[i], bfr[j], acc[i][j]);
    }

    // epilogue: C/D layout col=l16, row=quad*4+reg (m89/m91-verified)
    #pragma unroll
    for (int j = 0; j < 4; ++j) {
        const int col = o0 + wc * 64 + j * 16 + l16;
        const float bv = bias ? bias[col] : 0.0f;
        #pragma unroll
        for (int i = 0; i < 4; ++i) {
            const int row = m0 + wr * 64 + i * 16 + quad * 4;
            #pragma unroll
            for (int r = 0; r < 4; ++r) {
                const float v = acc[i][j][r] + bv;
                const size_t idx = (size_t)(row + r) * O + col;
                if (f32out) ((float*)Cout)[idx] = v;
                else        ((bf16*)Cout)[idx]  = __float2bfloat16(v);
            }
        }
    }
}

// ---------------------------------------------------------------------------
// Causal flash attention. qkv layout: [N][3C], Q at h*64, K at 1024+h*64,
// V at 2048+h*64. Block = 128 q rows x 1 head, 4 waves x 32 rows, KV tile 64.
// ---------------------------------------------------------------------------
constexpr int ATM = 128;   // q rows per block
constexpr int ATN = 64;    // kv tile

__global__ __launch_bounds__(256, 2) void attn_causal(
    const bf16* __restrict__ qkv, bf16* __restrict__ outp)
{
    __shared__ bf16 Ks[ATN * HD];       // [kv][d]   8 KB
    __shared__ bf16 VT[HD * ATN];       // [d][kv]   8 KB (V transposed)
    __shared__ bf16 Ps[4 * 32 * ATN];   // per-wave P [32][64]  16 KB

    const int tid  = threadIdx.x;
    const int wave = tid >> 6;
    const int lane = tid & 63;
    const int quad = lane >> 4;
    const int l16  = lane & 15;
    const int h    = blockIdx.y;
    const int q0   = blockIdx.x * ATM;
    const int qw   = q0 + wave * 32;

    // Q fragments: A[m=l16][k=quad*8+j], two k-chunks of 32 over D=64
    short8 qf[2][2];
    #pragma unroll
    for (int mi = 0; mi < 2; ++mi) {
        const bf16* qp = qkv + (size_t)(qw + mi * 16 + l16) * C3 + h * HD + quad * 8;
        qf[mi][0] = *(const short8*)qp;
        qf[mi][1] = *(const short8*)(qp + 32);
    }

    float m_i[2][4], l_i[2][4];
    f32x4 acc_o[2][4] = {};   // [mi][d-tile], rows=quad*4+r, col=l16
    #pragma unroll
    for (int mi = 0; mi < 2; ++mi)
        #pragma unroll
        for (int r = 0; r < 4; ++r) { m_i[mi][r] = -1e30f; l_i[mi][r] = 0.0f; }

    const int kv_end = q0 + ATM;   // exclusive; uniform across block
    for (int kv0 = 0; kv0 < kv_end; kv0 += ATN) {
        __syncthreads();
        {   // stage K [kv][d] and V transposed [d][kv]
            const int r   = tid >> 2;          // 0..63 kv row
            const int dch = (tid & 3) * 16;    // d chunk
            const bf16* kp = qkv + (size_t)(kv0 + r) * C3 + CC + h * HD + dch;
            *(short8*)&Ks[r * HD + dch]     = *(const short8*)kp;
            *(short8*)&Ks[r * HD + dch + 8] = *(const short8*)(kp + 8);
            const bf16* vp = qkv + (size_t)(kv0 + r) * C3 + 2 * CC + h * HD + dch;
            short8 v0 = *(const short8*)vp;
            short8 v1 = *(const short8*)(vp + 8);
            short* vt = (short*)VT;
            #pragma unroll
            for (int e = 0; e < 8; ++e) {
                vt[(dch + e) * ATN + r]     = v0[e];
                vt[(dch + 8 + e) * ATN + r] = v1[e];
            }
        }
        __syncthreads();

        // K fragments: B[k=d=quad*8+j][n=kv=l16]
        short8 kf[4][2];
        #pragma unroll
        for (int t = 0; t < 4; ++t) {
            kf[t][0] = *(const short8*)&Ks[(t * 16 + l16) * HD + quad * 8];
            kf[t][1] = *(const short8*)&Ks[(t * 16 + l16) * HD + 32 + quad * 8];
        }

        #pragma unroll
        for (int mi = 0; mi < 2; ++mi) {
            f32x4 accs[4] = {};
            #pragma unroll
            for (int t = 0; t < 4; ++t) {
                accs[t] = MFMA16(qf[mi][0], kf[t][0], accs[t]);
                accs[t] = MFMA16(qf[mi][1], kf[t][1], accs[t]);
            }
            float mx[4];
            #pragma unroll
            for (int r = 0; r < 4; ++r) {
                const int qrow = qw + mi * 16 + quad * 4 + r;
                float vmax = -1e30f;
                #pragma unroll
                for (int t = 0; t < 4; ++t) {
                    const int kvg = kv0 + t * 16 + l16;
                    float s = accs[t][r] * SCALE;
                    s = (kvg <= qrow) ? s : -1e30f;
                    accs[t][r] = s;
                    vmax = fmaxf(vmax, s);
                }
                mx[r] = vmax;
            }
            #pragma unroll
            for (int off = 1; off < 16; off <<= 1)
                #pragma unroll
                for (int r = 0; r < 4; ++r)
                    mx[r] = fmaxf(mx[r], __shfl_xor(mx[r], off, 64));

            float alpha[4], lsum[4];
            #pragma unroll
            for (int r = 0; r < 4; ++r) {
                const float mnew = fmaxf(m_i[mi][r], mx[r]);
                alpha[r] = __expf(m_i[mi][r] - mnew);
                m_i[mi][r] = mnew;
                float s = 0.0f;
                #pragma unroll
                for (int t = 0; t < 4; ++t) {
                    const float p = __expf(accs[t][r] - mnew);
                    accs[t][r] = p;
                    s += p;
                }
                lsum[r] = s;
            }
            #pragma unroll
            for (int off = 1; off < 16; off <<= 1)
                #pragma unroll
                for (int r = 0; r < 4; ++r)
                    lsum[r] += __shfl_xor(lsum[r], off, 64);
            #pragma unroll
            for (int r = 0; r < 4; ++r)
                l_i[mi][r] = l_i[mi][r] * alpha[r] + lsum[r];
            #pragma unroll
            for (int dt = 0; dt < 4; ++dt)
                #pragma unroll
                for (int r = 0; r < 4; ++r)
                    acc_o[mi][dt][r] *= alpha[r];

            // P: C-layout -> per-wave LDS region (wave-internal RAW only)
            #pragma unroll
            for (int t = 0; t < 4; ++t)
                #pragma unroll
                for (int r = 0; r < 4; ++r)
                    Ps[(wave * 32 + mi * 16 + quad * 4 + r) * ATN + t * 16 + l16] =
                        __float2bfloat16(accs[t][r]);
        }

        // PV: A[m=l16][k=kv=quad*8+j] from Ps; B[k=kv][n=d=l16] from VT
        #pragma unroll
        for (int c = 0; c < 2; ++c) {
            short8 vfr[4];
            #pragma unroll
            for (int dt = 0; dt < 4; ++dt)
                vfr[dt] = *(const short8*)&VT[(dt * 16 + l16) * ATN + c * 32 + quad * 8];
            #pragma unroll
            for (int mi = 0; mi < 2; ++mi) {
                short8 pf = *(const short8*)&Ps[(wave * 32 + mi * 16 + l16) * ATN + c * 32 + quad * 8];
                #pragma unroll
                for (int dt = 0; dt < 4; ++dt)
                    acc_o[mi][dt] = MFMA16(pf, vfr[dt], acc_o[mi][dt]);
            }
        }
    }

    // epilogue: divide by l, write [N][1024] bf16
    #pragma unroll
    for (int mi = 0; mi < 2; ++mi)
        #pragma unroll
        for (int r = 0; r < 4; ++r) {
            const int qrow = qw + mi * 16 + quad * 4 + r;
            const float inv = 1.0f / l_i[mi][r];
            #pragma unroll
            for (int dt = 0; dt < 4; ++dt)
                outp[(size_t)qrow * CC + h * HD + dt * 16 + l16] =
                    __float2bfloat16(acc_o[mi][dt][r] * inv);
        }
}

// ---------------------------------------------------------------------------
extern "C" void kernel_launch(void* const* d_in, const int* in_sizes, int n_in,
                              void* d_out, int out_size, void* d_ws, size_t ws_size,
                              hipStream_t stream) {
    char* ws = (char*)d_ws;
    bf16*  qkv      = (bf16*)(ws);                    // 24 MiB [4096][3072]
    bf16*  attn_out = (bf16*)(ws + 25165824);         //  8 MiB [4096][1024]
    bf16*  xb       = (bf16*)(ws + 33554432);         //  8 MiB [4096][1024]
    bf16*  wqkvb    = (bf16*)(ws + 41943040);         //  6 MiB [3072][1024]
    bf16*  wprojb   = (bf16*)(ws + 48234496);         //  2 MiB [1024][1024]
    float* biasf    = (float*)(ws + 50331648);        //  4 KiB
    int*   mode     = (int*)(ws + 50335744);

    // 1) dtype detect (writes mode flag)
    detect_mode<<<1, 64, 0, stream>>>((const unsigned short*)d_in[0], mode);
    // 2) convert inputs to bf16 (or copy if already bf16)
    cast_in<<<(AN * CC) / 8 / 256, 256, 0, stream>>>(d_in[0], xb, AN * CC, mode);
    cast_in<<<(C3 * CC) / 8 / 256, 256, 0, stream>>>(d_in[1], wqkvb, C3 * CC, mode);
    cast_in<<<(CC * CC) / 8 / 256, 256, 0, stream>>>(d_in[2], wprojb, CC * CC, mode);
    cast_bias<<<CC / 256, 256, 0, stream>>>(d_in[3], biasf, CC, mode);
    // 3) fused QKV projection (bf16 out to ws)
    gemm_bt<false><<<dim3(C3 / BN, AN / BM), 256, 0, stream>>>(
        xb, wqkvb, nullptr, qkv, mode, AN, CC, C3);
    // 4) causal flash attention per head
    attn_causal<<<dim3(AN / ATM, NH), 256, 0, stream>>>(qkv, attn_out);
    // 5) output projection + bias, store per detected output dtype
    gemm_bt<true><<<dim3(CC / BN, AN / BM), 256, 0, stream>>>(
        attn_out, wprojb, biasf, d_out, mode, AN, CC, CC);
}

// Round 3
// 315.469 us; speedup vs baseline: 1.3701x; 1.3701x over previous
//
#include <hip/hip_runtime.h>
#include <hip/hip_bf16.h>
#include <stdint.h>
#include <stddef.h>

using bf16 = __hip_bfloat16;
typedef short short8 __attribute__((ext_vector_type(8)));
typedef short short4v __attribute__((ext_vector_type(4)));
typedef float f32x4 __attribute__((ext_vector_type(4)));

#define MFMA16(A, B, C) __builtin_amdgcn_mfma_f32_16x16x32_bf16(A, B, C, 0, 0, 0)
#define GLOAD_LDS(g, l) __builtin_amdgcn_global_load_lds( \
    (const __attribute__((address_space(1))) void*)(g),   \
    (__attribute__((address_space(3))) void*)(l), 16, 0, 0)

// Problem constants
constexpr int AN  = 4096;   // sequence length N
constexpr int NH  = 16;     // heads
constexpr int HD  = 64;     // head dim
constexpr int CC  = 1024;   // channels = NH*HD
constexpr int C3  = 3072;   // 3*CC
// Q pre-scale: D^-0.5 * log2(e)  -> softmax runs in exp2 domain
constexpr float QSCALE = 0.125f * 1.4426950408889634f;

__device__ inline short bf16s(float f) {
    bf16 h = __float2bfloat16(f);
    return *reinterpret_cast<short*>(&h);
}

// ---------------------------------------------------------------------------
// Dtype auto-detect: mode=1 -> inputs fp32, mode=0 -> bf16.
// ---------------------------------------------------------------------------
__global__ void detect_mode(const unsigned short* __restrict__ xraw,
                            int* __restrict__ mode) {
    const int lane = threadIdx.x;   // 64 threads
    int crazy = 0;
    #pragma unroll
    for (int i = 0; i < 4; ++i) {
        const unsigned short u = xraw[lane * 4 + i];
        const int e = (u >> 7) & 0xFF;
        if (e >= 134 || (e != 0 && e <= 110)) ++crazy;
    }
    #pragma unroll
    for (int off = 32; off > 0; off >>= 1)
        crazy += __shfl_down(crazy, off, 64);
    if (lane == 0) *mode = (crazy >= 8) ? 1 : 0;
}

__global__ void cast_in(const void* __restrict__ src, bf16* __restrict__ dst,
                        int n, const int* __restrict__ mode) {
    const int i = (blockIdx.x * blockDim.x + threadIdx.x) * 8;
    if (i >= n) return;
    if (*mode) {
        const float* s = (const float*)src;
        float4 a = *(const float4*)(s + i);
        float4 b = *(const float4*)(s + i + 4);
        short8 o;
        o[0] = bf16s(a.x); o[1] = bf16s(a.y); o[2] = bf16s(a.z); o[3] = bf16s(a.w);
        o[4] = bf16s(b.x); o[5] = bf16s(b.y); o[6] = bf16s(b.z); o[7] = bf16s(b.w);
        *(short8*)(dst + i) = o;
    } else {
        *(short8*)(dst + i) = *(const short8*)((const short*)src + i);
    }
}

__global__ void cast_bias(const void* __restrict__ src, float* __restrict__ dst,
                          int n, const int* __restrict__ mode) {
    const int i = blockIdx.x * blockDim.x + threadIdx.x;
    if (i >= n) return;
    dst[i] = (*mode) ? ((const float*)src)[i]
                     : __bfloat162float(((const bf16*)src)[i]);
}

// ---------------------------------------------------------------------------
// GEMM (B-transposed weights): C[m][o] = sum_k A[m][k]*Bw[o][k] (+bias)
// MODE 0: plain bf16 out.  MODE 1: QKV special — Q cols scaled by QSCALE,
//   K cols plain, V cols written TRANSPOSED to vT[c][n].  MODE 2: final out,
//   dtype per *mode flag (fp32 vs bf16).
// ---------------------------------------------------------------------------
constexpr int BM = 128, BN = 128, BK = 32;

template<int MODE>
__global__ __launch_bounds__(256, 2) void gemm_bt(
    const bf16* __restrict__ A, const bf16* __restrict__ Bw,
    const float* __restrict__ bias, void* __restrict__ Cout,
    bf16* __restrict__ vTout, const int* __restrict__ mode,
    int M, int K, int O)
{
    __shared__ bf16 As[BM * BK];
    __shared__ bf16 Bs[BN * BK];

    const int tid  = threadIdx.x;
    const int wave = tid >> 6;
    const int lane = tid & 63;
    const int quad = lane >> 4;
    const int l16  = lane & 15;
    const int wr   = wave >> 1;
    const int wc   = wave & 1;
    const int m0   = blockIdx.y * BM;
    const int o0   = blockIdx.x * BN;

    const int srow = lane >> 2;
    const int scol = (lane & 3) * 8;

    f32x4 acc[4][4] = {};

    for (int k0 = 0; k0 < K; k0 += BK) {
        __syncthreads();
        #pragma unroll
        for (int c = 0; c < 2; ++c) {
            const int rbase = wave * 32 + c * 16;
            GLOAD_LDS(A + (size_t)(m0 + rbase + srow) * K + k0 + scol, &As[rbase * BK]);
            GLOAD_LDS(Bw + (size_t)(o0 + rbase + srow) * K + k0 + scol, &Bs[rbase * BK]);
        }
        __syncthreads();

        short8 af[4], bfr[4];
        #pragma unroll
        for (int i = 0; i < 4; ++i)
            af[i] = *(const short8*)&As[(wr * 64 + i * 16 + l16) * BK + quad * 8];
        #pragma unroll
        for (int j = 0; j < 4; ++j)
            bfr[j] = *(const short8*)&Bs[(wc * 64 + j * 16 + l16) * BK + quad * 8];
        #pragma unroll
        for (int i = 0; i < 4; ++i)
            #pragma unroll
            for (int j = 0; j < 4; ++j)
                acc[i][j] = MFMA16(af[i], bfr[j], acc[i][j]);
    }

    // epilogue: C/D layout col=l16, row=quad*4+reg
    if (MODE == 1 && o0 >= 2 * CC) {
        // V block -> vT[c][n], pack 4 consecutive rows into one 8B store
        #pragma unroll
        for (int j = 0; j < 4; ++j) {
            const int vc = o0 - 2 * CC + wc * 64 + j * 16 + l16;
            #pragma unroll
            for (int i = 0; i < 4; ++i) {
                const int row0 = m0 + wr * 64 + i * 16 + quad * 4;
                short4v pk;
                #pragma unroll
                for (int r = 0; r < 4; ++r) pk[r] = bf16s(acc[i][j][r]);
                *(short4v*)&vTout[(size_t)vc * AN + row0] = pk;
            }
        }
        return;
    }
    const float qs = (MODE == 1 && o0 < CC) ? QSCALE : 1.0f;
    const bool f32out = (MODE == 2) && (*mode != 0);
    #pragma unroll
    for (int j = 0; j < 4; ++j) {
        const int col = o0 + wc * 64 + j * 16 + l16;
        const float bv = bias ? bias[col] : 0.0f;
        #pragma unroll
        for (int i = 0; i < 4; ++i) {
            const int row = m0 + wr * 64 + i * 16 + quad * 4;
            #pragma unroll
            for (int r = 0; r < 4; ++r) {
                const float v = acc[i][j][r] * qs + bv;
                const size_t idx = (size_t)(row + r) * O + col;
                if (f32out) ((float*)Cout)[idx] = v;
                else        ((bf16*)Cout)[idx]  = __float2bfloat16(v);
            }
        }
    }
}

// ---------------------------------------------------------------------------
// Causal flash attention, pipelined.
// Block: 256 thr (4 waves x 16 q-rows), processes q-tiles (63-bx) then (bx)
// sequentially -> every block costs 33+-1 KV-iterations of 128. Grid 32x16.
// K staged [kv][d] and V staged from vT as [d][kv], both via global_load_lds.
// Loop: stage(it+1) -> compute(it) -> syncthreads (load latency hidden under
// a full tile of compute). Softmax in exp2 domain (Q pre-scaled).
// ---------------------------------------------------------------------------
constexpr int TK = 128;   // kv tile

__global__ __launch_bounds__(256, 2) void attn2(
    const bf16* __restrict__ qkv, const bf16* __restrict__ vT,
    bf16* __restrict__ outp)
{
    __shared__ bf16 Ks[2][TK * HD];    // [kv][d]  2 x 16 KB
    __shared__ bf16 Vs[2][HD * TK];    // [d][kv]  2 x 16 KB
    __shared__ bf16 Ps[4][16 * TK];    // per-wave P, swizzled  16 KB

    const int tid  = threadIdx.x;
    const int wave = tid >> 6;
    const int lane = tid & 63;
    const int quad = lane >> 4;
    const int l16  = lane & 15;
    const int h    = blockIdx.y;

    const int qts[2] = { 63 - (int)blockIdx.x, (int)blockIdx.x };

    for (int pass = 0; pass < 2; ++pass) {
        const int qt = qts[pass];
        const int q0 = qt * 64;
        const int qw = q0 + wave * 16;
        const int niter = qt / 2 + 1;

        // Q fragments (pre-scaled by QSCALE in the QKV GEMM)
        short8 qf0, qf1;
        {
            const bf16* qp = qkv + (size_t)(qw + l16) * C3 + h * HD + quad * 8;
            qf0 = *(const short8*)qp;
            qf1 = *(const short8*)(qp + 32);
        }

        float m_i[4], l_i[4];
        f32x4 acc_o[4] = {};
        #pragma unroll
        for (int r = 0; r < 4; ++r) { m_i[r] = -1e30f; l_i[r] = 0.0f; }

        // ---- staging: wave-cooperative async global->LDS ----
        auto stage = [&](int it, int p) {
            const int kv0 = it * TK;
            const int sr8 = lane >> 3, sc8 = (lane & 7) * 8;
            #pragma unroll
            for (int c = 0; c < 4; ++c) {
                const int rb = wave * 32 + c * 8;   // kv rows, wave-uniform base
                GLOAD_LDS(qkv + (size_t)(kv0 + rb + sr8) * C3 + CC + h * HD + sc8,
                          &Ks[p][rb * HD]);
            }
            const int sr16 = lane >> 4, sc16 = (lane & 15) * 8;
            #pragma unroll
            for (int c = 0; c < 4; ++c) {
                const int rb = wave * 16 + c * 4;   // d rows, wave-uniform base
                GLOAD_LDS(vT + (size_t)(h * HD + rb + sr16) * AN + kv0 + sc16,
                          &Vs[p][rb * TK]);
            }
        };

        stage(0, 0);
        __syncthreads();

        for (int it = 0; it < niter; ++it) {
            const int p = it & 1;
            if (it + 1 < niter) stage(it + 1, p ^ 1);   // async prefetch

            // ---- QK^T: S[m=q][n=kv], A=Q frag, B from Ks ----
            f32x4 accs[8];
            #pragma unroll
            for (int t = 0; t < 8; ++t) {
                short8 k0 = *(const short8*)&Ks[p][(t * 16 + l16) * HD + quad * 8];
                short8 k1 = *(const short8*)&Ks[p][(t * 16 + l16) * HD + 32 + quad * 8];
                f32x4 a = {};
                a = MFMA16(qf0, k0, a);
                a = MFMA16(qf1, k1, a);
                accs[t] = a;
            }

            const int kv0 = it * TK;
            const bool diag = (it == niter - 1);   // block-uniform

            // ---- online softmax (exp2 domain); rows at (quad,reg) ----
            float mx[4];
            #pragma unroll
            for (int r = 0; r < 4; ++r) {
                float vm = -1e30f;
                if (diag) {
                    const int qrow = qw + quad * 4 + r;
                    #pragma unroll
                    for (int t = 0; t < 8; ++t) {
                        const int kvg = kv0 + t * 16 + l16;
                        float s = (kvg <= qrow) ? accs[t][r] : -1e30f;
                        accs[t][r] = s;
                        vm = fmaxf(vm, s);
                    }
                } else {
                    #pragma unroll
                    for (int t = 0; t < 8; ++t) vm = fmaxf(vm, accs[t][r]);
                }
                mx[r] = vm;
            }
            #pragma unroll
            for (int off = 1; off < 16; off <<= 1)
                #pragma unroll
                for (int r = 0; r < 4; ++r)
                    mx[r] = fmaxf(mx[r], __shfl_xor(mx[r], off, 64));

            float alpha[4], ls[4];
            #pragma unroll
            for (int r = 0; r < 4; ++r) {
                const float mnew = fmaxf(m_i[r], mx[r]);
                alpha[r] = exp2f(m_i[r] - mnew);
                m_i[r] = mnew;
                float s = 0.0f;
                #pragma unroll
                for (int t = 0; t < 8; ++t) {
                    const float pv = exp2f(accs[t][r] - mnew);
                    accs[t][r] = pv;
                    s += pv;
                }
                ls[r] = s;
            }
            #pragma unroll
            for (int off = 1; off < 16; off <<= 1)
                #pragma unroll
                for (int r = 0; r < 4; ++r)
                    ls[r] += __shfl_xor(ls[r], off, 64);
            #pragma unroll
            for (int r = 0; r < 4; ++r)
                l_i[r] = l_i[r] * alpha[r] + ls[r];
            #pragma unroll
            for (int dt = 0; dt < 4; ++dt)
                #pragma unroll
                for (int r = 0; r < 4; ++r)
                    acc_o[dt][r] *= alpha[r];

            // ---- P -> LDS, XOR-swizzled (bank-conflict free) ----
            #pragma unroll
            for (int t = 0; t < 8; ++t) {
                const int pc = (t * 16 + l16) ^ (quad << 4);
                #pragma unroll
                for (int r = 0; r < 4; ++r)
                    Ps[wave][(quad * 4 + r) * TK + pc] = __float2bfloat16(accs[t][r]);
            }

            // ---- PV: A=P frag (swizzled read), B from Vs ----
            #pragma unroll
            for (int c = 0; c < 4; ++c) {
                const int pcol = (c * 32 + quad * 8) ^ (((l16 >> 2) & 3) << 4);
                short8 pf = *(const short8*)&Ps[wave][l16 * TK + pcol];
                #pragma unroll
                for (int dt = 0; dt < 4; ++dt) {
                    short8 vf = *(const short8*)&Vs[p][(dt * 16 + l16) * TK + c * 32 + quad * 8];
                    acc_o[dt] = MFMA16(pf, vf, acc_o[dt]);
                }
            }
            __syncthreads();   // drains prefetch; syncs buffer reuse
        }

        // ---- epilogue ----
        #pragma unroll
        for (int r = 0; r < 4; ++r) {
            const int qrow = qw + quad * 4 + r;
            const float inv = 1.0f / l_i[r];
            #pragma unroll
            for (int dt = 0; dt < 4; ++dt)
                outp[(size_t)qrow * CC + h * HD + dt * 16 + l16] =
                    __float2bfloat16(acc_o[dt][r] * inv);
        }
    }
}

// ---------------------------------------------------------------------------
extern "C" void kernel_launch(void* const* d_in, const int* in_sizes, int n_in,
                              void* d_out, int out_size, void* d_ws, size_t ws_size,
                              hipStream_t stream) {
    char* ws = (char*)d_ws;
    bf16*  qkv      = (bf16*)(ws);                    // 24 MiB [4096][3072] (V third unused)
    bf16*  attn_out = (bf16*)(ws + 25165824);         //  8 MiB [4096][1024]
    bf16*  vT       = (bf16*)(ws + 33554432);         //  8 MiB [1024][4096]
    bf16*  xb       = (bf16*)(ws + 41943040);         //  8 MiB
    bf16*  wqkvb    = (bf16*)(ws + 50331648);         //  6 MiB
    bf16*  wprojb   = (bf16*)(ws + 56623104);         //  2 MiB
    float* biasf    = (float*)(ws + 58720256);        //  4 KiB
    int*   mode     = (int*)(ws + 58724352);

    detect_mode<<<1, 64, 0, stream>>>((const unsigned short*)d_in[0], mode);
    cast_in<<<(AN * CC) / 8 / 256, 256, 0, stream>>>(d_in[0], xb, AN * CC, mode);
    cast_in<<<(C3 * CC) / 8 / 256, 256, 0, stream>>>(d_in[1], wqkvb, C3 * CC, mode);
    cast_in<<<(CC * CC) / 8 / 256, 256, 0, stream>>>(d_in[2], wprojb, CC * CC, mode);
    cast_bias<<<CC / 256, 256, 0, stream>>>(d_in[3], biasf, CC, mode);

    // QKV projection: Q scaled, K plain into qkv; V transposed into vT
    gemm_bt<1><<<dim3(C3 / BN, AN / BM), 256, 0, stream>>>(
        xb, wqkvb, nullptr, qkv, vT, mode, AN, CC, C3);
    // causal flash attention (paired q-tiles, pipelined)
    attn2<<<dim3(32, NH), 256, 0, stream>>>(qkv, vT, attn_out);
    // output projection + bias
    gemm_bt<2><<<dim3(CC / BN, AN / BM), 256, 0, stream>>>(
        attn_out, wprojb, biasf, d_out, nullptr, mode, AN, CC, CC);
}

// Round 4
// 233.981 us; speedup vs baseline: 1.8473x; 1.3483x over previous
//
#include <hip/hip_runtime.h>
#include <hip/hip_bf16.h>
#include <stdint.h>
#include <stddef.h>

using bf16 = __hip_bfloat16;
typedef short short8 __attribute__((ext_vector_type(8)));
typedef short short4v __attribute__((ext_vector_type(4)));
typedef short short2v __attribute__((ext_vector_type(2)));
typedef float f32x4 __attribute__((ext_vector_type(4)));

#define MFMA16(A, B, C) __builtin_amdgcn_mfma_f32_16x16x32_bf16(A, B, C, 0, 0, 0)
#define MFMA16K16(A, B, C) __builtin_amdgcn_mfma_f32_16x16x16bf16_1k(A, B, C, 0, 0, 0)
#define GLOAD_LDS(g, l) __builtin_amdgcn_global_load_lds( \
    (const __attribute__((address_space(1))) void*)(g),   \
    (__attribute__((address_space(3))) void*)(l), 16, 0, 0)

// Problem constants
constexpr int AN  = 4096;   // sequence length N
constexpr int NH  = 16;     // heads
constexpr int HD  = 64;     // head dim
constexpr int CC  = 1024;   // channels = NH*HD
constexpr int C3  = 3072;   // 3*CC
// Q pre-scale: D^-0.5 * log2(e)  -> softmax runs in exp2 domain
constexpr float QSCALE = 0.125f * 1.4426950408889634f;

__device__ inline short bf16s(float f) {
    bf16 h = __float2bfloat16(f);
    return *reinterpret_cast<short*>(&h);
}

// ---------------------------------------------------------------------------
// Dtype auto-detect: mode=1 -> inputs fp32, mode=0 -> bf16.
// ---------------------------------------------------------------------------
__global__ void detect_mode(const unsigned short* __restrict__ xraw,
                            int* __restrict__ mode) {
    const int lane = threadIdx.x;   // 64 threads
    int crazy = 0;
    #pragma unroll
    for (int i = 0; i < 4; ++i) {
        const unsigned short u = xraw[lane * 4 + i];
        const int e = (u >> 7) & 0xFF;
        if (e >= 134 || (e != 0 && e <= 110)) ++crazy;
    }
    #pragma unroll
    for (int off = 32; off > 0; off >>= 1)
        crazy += __shfl_down(crazy, off, 64);
    if (lane == 0) *mode = (crazy >= 8) ? 1 : 0;
}

__global__ void cast_in(const void* __restrict__ src, bf16* __restrict__ dst,
                        int n, const int* __restrict__ mode) {
    const int i = (blockIdx.x * blockDim.x + threadIdx.x) * 8;
    if (i >= n) return;
    if (*mode) {
        const float* s = (const float*)src;
        float4 a = *(const float4*)(s + i);
        float4 b = *(const float4*)(s + i + 4);
        short8 o;
        o[0] = bf16s(a.x); o[1] = bf16s(a.y); o[2] = bf16s(a.z); o[3] = bf16s(a.w);
        o[4] = bf16s(b.x); o[5] = bf16s(b.y); o[6] = bf16s(b.z); o[7] = bf16s(b.w);
        *(short8*)(dst + i) = o;
    } else {
        *(short8*)(dst + i) = *(const short8*)((const short*)src + i);
    }
}

__global__ void cast_bias(const void* __restrict__ src, float* __restrict__ dst,
                          int n, const int* __restrict__ mode) {
    const int i = blockIdx.x * blockDim.x + threadIdx.x;
    if (i >= n) return;
    dst[i] = (*mode) ? ((const float*)src)[i]
                     : __bfloat162float(((const bf16*)src)[i]);
}

// ---------------------------------------------------------------------------
// GEMM (B-transposed weights): C[m][o] = sum_k A[m][k]*Bw[o][k] (+bias)
// MODE 1: QKV special — Q cols scaled by QSCALE, K cols plain, V cols
//   written TRANSPOSED to vT[c][n].  MODE 2: final out, dtype per *mode flag.
// ---------------------------------------------------------------------------
constexpr int BM = 128, BN = 128, BK = 32;

template<int MODE>
__global__ __launch_bounds__(256, 2) void gemm_bt(
    const bf16* __restrict__ A, const bf16* __restrict__ Bw,
    const float* __restrict__ bias, void* __restrict__ Cout,
    bf16* __restrict__ vTout, const int* __restrict__ mode,
    int M, int K, int O)
{
    __shared__ bf16 As[BM * BK];
    __shared__ bf16 Bs[BN * BK];

    const int tid  = threadIdx.x;
    const int wave = tid >> 6;
    const int lane = tid & 63;
    const int quad = lane >> 4;
    const int l16  = lane & 15;
    const int wr   = wave >> 1;
    const int wc   = wave & 1;
    const int m0   = blockIdx.y * BM;
    const int o0   = blockIdx.x * BN;

    const int srow = lane >> 2;
    const int scol = (lane & 3) * 8;

    f32x4 acc[4][4] = {};

    for (int k0 = 0; k0 < K; k0 += BK) {
        __syncthreads();
        #pragma unroll
        for (int c = 0; c < 2; ++c) {
            const int rbase = wave * 32 + c * 16;
            GLOAD_LDS(A + (size_t)(m0 + rbase + srow) * K + k0 + scol, &As[rbase * BK]);
            GLOAD_LDS(Bw + (size_t)(o0 + rbase + srow) * K + k0 + scol, &Bs[rbase * BK]);
        }
        __syncthreads();

        short8 af[4], bfr[4];
        #pragma unroll
        for (int i = 0; i < 4; ++i)
            af[i] = *(const short8*)&As[(wr * 64 + i * 16 + l16) * BK + quad * 8];
        #pragma unroll
        for (int j = 0; j < 4; ++j)
            bfr[j] = *(const short8*)&Bs[(wc * 64 + j * 16 + l16) * BK + quad * 8];
        #pragma unroll
        for (int i = 0; i < 4; ++i)
            #pragma unroll
            for (int j = 0; j < 4; ++j)
                acc[i][j] = MFMA16(af[i], bfr[j], acc[i][j]);
    }

    // epilogue: C/D layout col=l16, row=quad*4+reg
    if (MODE == 1 && o0 >= 2 * CC) {
        // V block -> vT[c][n], pack 4 consecutive rows into one 8B store
        #pragma unroll
        for (int j = 0; j < 4; ++j) {
            const int vc = o0 - 2 * CC + wc * 64 + j * 16 + l16;
            #pragma unroll
            for (int i = 0; i < 4; ++i) {
                const int row0 = m0 + wr * 64 + i * 16 + quad * 4;
                short4v pk;
                #pragma unroll
                for (int r = 0; r < 4; ++r) pk[r] = bf16s(acc[i][j][r]);
                *(short4v*)&vTout[(size_t)vc * AN + row0] = pk;
            }
        }
        return;
    }
    const float qs = (MODE == 1 && o0 < CC) ? QSCALE : 1.0f;
    const bool f32out = (MODE == 2) && (*mode != 0);
    #pragma unroll
    for (int j = 0; j < 4; ++j) {
        const int col = o0 + wc * 64 + j * 16 + l16;
        const float bv = bias ? bias[col] : 0.0f;
        #pragma unroll
        for (int i = 0; i < 4; ++i) {
            const int row = m0 + wr * 64 + i * 16 + quad * 4;
            #pragma unroll
            for (int r = 0; r < 4; ++r) {
                const float v = acc[i][j][r] * qs + bv;
                const size_t idx = (size_t)(row + r) * O + col;
                if (f32out) ((float*)Cout)[idx] = v;
                else        ((bf16*)Cout)[idx]  = __float2bfloat16(v);
            }
        }
    }
}

// ---------------------------------------------------------------------------
// Causal flash attention, S-transposed formulation.
// Sᵀ = K·Qᵀ via mfma_16x16x32 (operands swapped): C-layout col=l16=q,
// row=quad*4+r=kv — which IS the B-operand layout of mfma_16x16x16, so
// P feeds PV straight from registers (no LDS round-trip, no transpose).
// O accumulates transposed (row=d, col=q). Softmax state: 1 scalar/lane.
//
// Grid: 1024 1-D blocks, 4 waves, q-tile 64 (16 rows/wave), TK=64 kv tiles.
// qt = perm(v) so the 4 co-resident blocks (id stride 256) have niters
// summing to a constant 130 -> balanced CUs at 16 waves/CU.
// K/V staged via global_load_lds with 16B-chunk XOR swizzle
// (phys_chunk = logical ^ (row&7)) -> fragment reads <=2-way conflicts.
// ---------------------------------------------------------------------------
constexpr int TK = 64;   // kv tile

__global__ __launch_bounds__(256, 4) void attn3(
    const bf16* __restrict__ qkv, const bf16* __restrict__ vT,
    bf16* __restrict__ outp)
{
    __shared__ bf16 Ks[2][TK * HD];    // [kv][d] swizzled, 2 x 8 KB
    __shared__ bf16 Vs[2][HD * TK];    // [d][kv] swizzled, 2 x 8 KB

    const int tid  = threadIdx.x;
    const int wave = tid >> 6;
    const int lane = tid & 63;
    const int quad = lane >> 4;
    const int l16  = lane & 15;
    const int h7   = l16 & 7;

    const int h  = blockIdx.x & 15;
    const int v  = blockIdx.x >> 4;           // 0..63
    const int qt = (v < 32) ? v : 95 - v;     // complement permutation
    const int q0 = qt * 64;
    const int qw = q0 + wave * 16;
    const int niter = qt + 1;

    // Q fragment (pre-scaled by QSCALE*log2e in QKV GEMM); serves as B operand
    short8 qf0, qf1;
    {
        const bf16* qp = qkv + (size_t)(qw + l16) * C3 + h * HD + quad * 8;
        qf0 = *(const short8*)qp;
        qf1 = *(const short8*)(qp + 32);
    }

    float m_i = -1e30f, l_i = 0.0f;
    f32x4 acc_o[4] = {};   // Oᵀ: row d = dt*16+quad*4+r, col q = l16

    // staging: 4 global_load_lds per wave; phys chunk pc holds logical
    // chunk pc^(row&7)
    auto stage = [&](int it, int p) {
        const int kv0 = it * TK;
        const int sr = lane >> 3;        // row within 8-row call
        const int pc = lane & 7;         // phys 16B chunk
        #pragma unroll
        for (int c = 0; c < 2; ++c) {
            const int rb  = wave * 16 + c * 8;   // wave-uniform base row
            const int row = rb + sr;
            const int lc  = pc ^ (row & 7);      // logical chunk to fetch
            GLOAD_LDS(qkv + (size_t)(kv0 + row) * C3 + CC + h * HD + lc * 8,
                      &Ks[p][rb * HD]);
            GLOAD_LDS(vT + (size_t)(h * HD + row) * AN + kv0 + lc * 8,
                      &Vs[p][rb * TK]);
        }
    };

    stage(0, 0);
    __syncthreads();

    for (int it = 0; it < niter; ++it) {
        const int p = it & 1;
        if (it + 1 < niter) stage(it + 1, p ^ 1);   // async prefetch

        // ---- Sᵀ = K·Qᵀ: A=K frag (m=kv), B=Q frag (n=q) ----
        f32x4 st[4];
        #pragma unroll
        for (int t = 0; t < 4; ++t) {
            const int row = t * 16 + l16;          // kv row; row&7 == h7
            short8 kf0 = *(const short8*)&Ks[p][row * HD + ((quad ^ h7) * 8)];
            short8 kf1 = *(const short8*)&Ks[p][row * HD + (((quad + 4) ^ h7) * 8)];
            f32x4 a = {};
            a = MFMA16(kf0, qf0, a);
            a = MFMA16(kf1, qf1, a);
            st[t] = a;
        }

        const int kv0 = it * TK;
        const bool diag = (it == niter - 1);   // block-uniform

        // ---- online softmax over kv (in-lane + 2 shuffles) ----
        float mx = -1e30f;
        if (diag) {
            const int q = qw + l16;
            #pragma unroll
            for (int t = 0; t < 4; ++t)
                #pragma unroll
                for (int r = 0; r < 4; ++r) {
                    const int kv = kv0 + t * 16 + quad * 4 + r;
                    float s = (kv <= q) ? st[t][r] : -1e30f;
                    st[t][r] = s;
                    mx = fmaxf(mx, s);
                }
        } else {
            #pragma unroll
            for (int t = 0; t < 4; ++t)
                #pragma unroll
                for (int r = 0; r < 4; ++r)
                    mx = fmaxf(mx, st[t][r]);
        }
        mx = fmaxf(mx, __shfl_xor(mx, 16, 64));
        mx = fmaxf(mx, __shfl_xor(mx, 32, 64));

        const float mnew = fmaxf(m_i, mx);
        const float alpha = exp2f(m_i - mnew);
        m_i = mnew;
        float ls = 0.0f;
        #pragma unroll
        for (int t = 0; t < 4; ++t)
            #pragma unroll
            for (int r = 0; r < 4; ++r) {
                const float pv = exp2f(st[t][r] - mnew);
                st[t][r] = pv;
                ls += pv;
            }
        ls += __shfl_xor(ls, 16, 64);
        ls += __shfl_xor(ls, 32, 64);
        l_i = l_i * alpha + ls;
        #pragma unroll
        for (int dt = 0; dt < 4; ++dt)
            #pragma unroll
            for (int r = 0; r < 4; ++r)
                acc_o[dt][r] *= alpha;

        // ---- PV: Oᵀ += Vᵀ·Pᵀ via mfma_16x16x16; P is already B-layout ----
        #pragma unroll
        for (int t = 0; t < 4; ++t) {
            short4v bp;
            #pragma unroll
            for (int j = 0; j < 4; ++j) bp[j] = bf16s(st[t][j]);
            const int pc2 = (2 * t + (quad >> 1)) ^ h7;   // phys 16B chunk
            #pragma unroll
            for (int dt = 0; dt < 4; ++dt) {
                const int row = dt * 16 + l16;            // d row; row&7 == h7
                short4v vf = *(const short4v*)&Vs[p][row * TK + pc2 * 8 + (quad & 1) * 4];
                acc_o[dt] = MFMA16K16(vf, bp, acc_o[dt]);
            }
        }
        __syncthreads();   // drains prefetch; orders buffer reuse
    }

    // ---- epilogue: divide by l, write [token][channel] bf16 ----
    const float inv = 1.0f / l_i;
    const size_t base = (size_t)(qw + l16) * CC + h * HD;
    #pragma unroll
    for (int dt = 0; dt < 4; ++dt) {
        const int d0 = dt * 16 + quad * 4;
        short2v p0, p1;
        p0[0] = bf16s(acc_o[dt][0] * inv); p0[1] = bf16s(acc_o[dt][1] * inv);
        p1[0] = bf16s(acc_o[dt][2] * inv); p1[1] = bf16s(acc_o[dt][3] * inv);
        *(short2v*)&outp[base + d0]     = p0;
        *(short2v*)&outp[base + d0 + 2] = p1;
    }
}

// ---------------------------------------------------------------------------
extern "C" void kernel_launch(void* const* d_in, const int* in_sizes, int n_in,
                              void* d_out, int out_size, void* d_ws, size_t ws_size,
                              hipStream_t stream) {
    char* ws = (char*)d_ws;
    bf16*  qkv      = (bf16*)(ws);                    // 24 MiB [4096][3072] (V third unused)
    bf16*  attn_out = (bf16*)(ws + 25165824);         //  8 MiB [4096][1024]
    bf16*  vT       = (bf16*)(ws + 33554432);         //  8 MiB [1024][4096]
    bf16*  xb       = (bf16*)(ws + 41943040);         //  8 MiB
    bf16*  wqkvb    = (bf16*)(ws + 50331648);         //  6 MiB
    bf16*  wprojb   = (bf16*)(ws + 56623104);         //  2 MiB
    float* biasf    = (float*)(ws + 58720256);        //  4 KiB
    int*   mode     = (int*)(ws + 58724352);

    detect_mode<<<1, 64, 0, stream>>>((const unsigned short*)d_in[0], mode);
    cast_in<<<(AN * CC) / 8 / 256, 256, 0, stream>>>(d_in[0], xb, AN * CC, mode);
    cast_in<<<(C3 * CC) / 8 / 256, 256, 0, stream>>>(d_in[1], wqkvb, C3 * CC, mode);
    cast_in<<<(CC * CC) / 8 / 256, 256, 0, stream>>>(d_in[2], wprojb, CC * CC, mode);
    cast_bias<<<CC / 256, 256, 0, stream>>>(d_in[3], biasf, CC, mode);

    // QKV projection: Q scaled, K plain into qkv; V transposed into vT
    gemm_bt<1><<<dim3(C3 / BN, AN / BM), 256, 0, stream>>>(
        xb, wqkvb, nullptr, qkv, vT, mode, AN, CC, C3);
    // causal flash attention (S-transposed, balanced 1-D grid)
    attn3<<<dim3(64 * NH), 256, 0, stream>>>(qkv, vT, attn_out);
    // output projection + bias
    gemm_bt<2><<<dim3(CC / BN, AN / BM), 256, 0, stream>>>(
        attn_out, wprojb, biasf, d_out, nullptr, mode, AN, CC, CC);
}